// Round 11
// baseline (391.708 us; speedup 1.0000x reference)
//
#include <hip/hip_runtime.h>
#include <hip/hip_bf16.h>
#include <math.h>

// AttentionDownSample: fm [8,128,256,256] f32, Wq/Wk [32,128] f32
// out [8,128,128,128] f32.
//
// r11: read-fm-once bf16 register stash (r10 algebra) re-engineered for
// occupancy: 256-thread blocks (512-thr blocks measured ~1 block/CU all
// session), <=64 VGPRs (the m69 occupancy cliff), 16.5 KB LDS.
//   Block = 32 positions x 8 channel groups (16 ch/thread).
//   r-dimension split in two sequential halves so only 16 Q-accumulators
//   (pass 1a/1b) or 16 Q-operands (pass 2a/2b) are live at once:
//     pass1a: qa[r=0..15]  += WqT'[c][r] * u[c]   -> tree-reduce to QsA
//     pass1b: qa[r=16..31] ...                    -> tree-reduce to QsB
//     pass2a: t_lo[c] = sum_{r<16} Q[r] WkT[c][r]; logits += t_lo*v_s
//     pass2b: same with Q[16..31] (logit linear in r-split => exact)
//     softmax over s=4; pass3: out = sum_s attn_s v_s  (from stash)
// Weights: per-lane vector loads (cq not wave-uniform; 2 addrs/wave, L1/L2
// broadcast, total 32 KB hot). fm: vector global loads, read exactly once.
// __launch_bounds__(256,8) pins the 64-VGPR budget (steady need ~58).

typedef unsigned int uint32;

__device__ __forceinline__ uint32 pack2(float x, float y) {
  union { __hip_bfloat162 h; uint32 u; } cvt;
  cvt.h = __float22bfloat162_rn(make_float2(x, y));
  return cvt.u;
}
__device__ __forceinline__ float2 unpack2(uint32 u) {
  float2 r;
  r.x = __uint_as_float(u << 16);
  r.y = __uint_as_float(u & 0xffff0000u);
  return r;
}

__global__ __launch_bounds__(256) void wt_kernel(const float* __restrict__ Wq,
                                                 const float* __restrict__ Wk,
                                                 float* __restrict__ ws) {
  int t = blockIdx.x * 256 + threadIdx.x;  // 4096 threads, one (c,r) each
  if (t < 4096) {
    int c = t >> 5, r = t & 31;
    ws[c * 32 + r]        = Wq[r * 128 + c] * (0.25f / sqrtf(32.0f));
    ws[4096 + c * 32 + r] = Wk[r * 128 + c];
  }
}

__global__ __launch_bounds__(256, 8)
void attn_main(const float* __restrict__ fm,
               const float* __restrict__ ws,
               float* __restrict__ out) {
  __shared__ float QsA[4 * 16 * 32];  // 8 KB: Qlo tree; later lbuf alias
  __shared__ float QsB[4 * 16 * 32];  // 8 KB: Qhi tree; later abuf alias

  const int tid = threadIdx.x;
  const int p   = tid & 31;        // position within 32-wide tile
  const int cq  = tid >> 5;        // channel group 0..7 (16 ch each)

  const int blk = blockIdx.x;      // 4096 = 8 b * 128 h * 4 wq
  const int w0  = (blk & 3) * 32;
  const int h   = (blk >> 2) & 127;
  const int b   = blk >> 9;
  const int cb  = cq * 16;

  const float* gbase = fm + ((size_t)(b * 128 + cb)) * 65536 +
                       (size_t)(2 * h) * 256 + 2 * (w0 + p);
  const float* wqp = ws + cb * 32;          // WqT'[c][r]
  const float* wkp = ws + 4096 + cb * 32;   // WkT[c][r]

  // ---- phase M: read this thread's fm slice ONCE -> bf16x2 stash ----
  uint32 pka[16], pkb[16];
#pragma unroll
  for (int i = 0; i < 16; ++i) {
    const float2 va = *(const float2*)(gbase + (size_t)i * 65536);        // row0
    const float2 vb = *(const float2*)(gbase + (size_t)i * 65536 + 256);  // row1
    pka[i] = pack2(va.x, va.y);
    pkb[i] = pack2(vb.x, vb.y);
  }

  float qa[16];

  // ---- pass 1a: partial Q, r = 0..15 ----
#pragma unroll
  for (int r = 0; r < 16; ++r) qa[r] = 0.f;
#pragma unroll
  for (int i = 0; i < 16; ++i) {
    const float2 va = unpack2(pka[i]);
    const float2 vb = unpack2(pkb[i]);
    const float u = (va.x + va.y) + (vb.x + vb.y);
    const float4 w0_ = *(const float4*)(wqp + i * 32 + 0);
    const float4 w1_ = *(const float4*)(wqp + i * 32 + 4);
    const float4 w2_ = *(const float4*)(wqp + i * 32 + 8);
    const float4 w3_ = *(const float4*)(wqp + i * 32 + 12);
    qa[0]  = fmaf(w0_.x, u, qa[0]);
    qa[1]  = fmaf(w0_.y, u, qa[1]);
    qa[2]  = fmaf(w0_.z, u, qa[2]);
    qa[3]  = fmaf(w0_.w, u, qa[3]);
    qa[4]  = fmaf(w1_.x, u, qa[4]);
    qa[5]  = fmaf(w1_.y, u, qa[5]);
    qa[6]  = fmaf(w1_.z, u, qa[6]);
    qa[7]  = fmaf(w1_.w, u, qa[7]);
    qa[8]  = fmaf(w2_.x, u, qa[8]);
    qa[9]  = fmaf(w2_.y, u, qa[9]);
    qa[10] = fmaf(w2_.z, u, qa[10]);
    qa[11] = fmaf(w2_.w, u, qa[11]);
    qa[12] = fmaf(w3_.x, u, qa[12]);
    qa[13] = fmaf(w3_.y, u, qa[13]);
    qa[14] = fmaf(w3_.z, u, qa[14]);
    qa[15] = fmaf(w3_.w, u, qa[15]);
  }
  // tree-reduce 8 -> 4 -> 2 (final = [0]+[1], summed at point of use)
  if (cq >= 4) {
#pragma unroll
    for (int r = 0; r < 16; ++r) QsA[(cq - 4) * 512 + r * 32 + p] = qa[r];
  }
  __syncthreads();
  if (cq < 4) {
#pragma unroll
    for (int r = 0; r < 16; ++r) QsA[cq * 512 + r * 32 + p] += qa[r];
  }
  __syncthreads();
  if (cq < 2) {
#pragma unroll
    for (int r = 0; r < 16; ++r)
      QsA[cq * 512 + r * 32 + p] += QsA[(cq + 2) * 512 + r * 32 + p];
  }
  __syncthreads();

  // ---- pass 1b: partial Q, r = 16..31 ----
#pragma unroll
  for (int r = 0; r < 16; ++r) qa[r] = 0.f;
#pragma unroll
  for (int i = 0; i < 16; ++i) {
    const float2 va = unpack2(pka[i]);
    const float2 vb = unpack2(pkb[i]);
    const float u = (va.x + va.y) + (vb.x + vb.y);
    const float4 w0_ = *(const float4*)(wqp + i * 32 + 16);
    const float4 w1_ = *(const float4*)(wqp + i * 32 + 20);
    const float4 w2_ = *(const float4*)(wqp + i * 32 + 24);
    const float4 w3_ = *(const float4*)(wqp + i * 32 + 28);
    qa[0]  = fmaf(w0_.x, u, qa[0]);
    qa[1]  = fmaf(w0_.y, u, qa[1]);
    qa[2]  = fmaf(w0_.z, u, qa[2]);
    qa[3]  = fmaf(w0_.w, u, qa[3]);
    qa[4]  = fmaf(w1_.x, u, qa[4]);
    qa[5]  = fmaf(w1_.y, u, qa[5]);
    qa[6]  = fmaf(w1_.z, u, qa[6]);
    qa[7]  = fmaf(w1_.w, u, qa[7]);
    qa[8]  = fmaf(w2_.x, u, qa[8]);
    qa[9]  = fmaf(w2_.y, u, qa[9]);
    qa[10] = fmaf(w2_.z, u, qa[10]);
    qa[11] = fmaf(w2_.w, u, qa[11]);
    qa[12] = fmaf(w3_.x, u, qa[12]);
    qa[13] = fmaf(w3_.y, u, qa[13]);
    qa[14] = fmaf(w3_.z, u, qa[14]);
    qa[15] = fmaf(w3_.w, u, qa[15]);
  }
  if (cq >= 4) {
#pragma unroll
    for (int r = 0; r < 16; ++r) QsB[(cq - 4) * 512 + r * 32 + p] = qa[r];
  }
  __syncthreads();
  if (cq < 4) {
#pragma unroll
    for (int r = 0; r < 16; ++r) QsB[cq * 512 + r * 32 + p] += qa[r];
  }
  __syncthreads();
  if (cq < 2) {
#pragma unroll
    for (int r = 0; r < 16; ++r)
      QsB[cq * 512 + r * 32 + p] += QsB[(cq + 2) * 512 + r * 32 + p];
  }
  __syncthreads();

  // ---- pass 2a: logits with Q[0..15] ----
  float l0 = 0.f, l1 = 0.f, l2 = 0.f, l3 = 0.f;
  {
    float qh[16];
#pragma unroll
    for (int r = 0; r < 16; ++r)
      qh[r] = QsA[r * 32 + p] + QsA[512 + r * 32 + p];
#pragma unroll
    for (int i = 0; i < 16; ++i) {
      const float4 k0 = *(const float4*)(wkp + i * 32 + 0);
      const float4 k1 = *(const float4*)(wkp + i * 32 + 4);
      const float4 k2 = *(const float4*)(wkp + i * 32 + 8);
      const float4 k3 = *(const float4*)(wkp + i * 32 + 12);
      float t0 = 0.f, t1 = 0.f;
      t0 = fmaf(qh[0],  k0.x, t0); t1 = fmaf(qh[1],  k0.y, t1);
      t0 = fmaf(qh[2],  k0.z, t0); t1 = fmaf(qh[3],  k0.w, t1);
      t0 = fmaf(qh[4],  k1.x, t0); t1 = fmaf(qh[5],  k1.y, t1);
      t0 = fmaf(qh[6],  k1.z, t0); t1 = fmaf(qh[7],  k1.w, t1);
      t0 = fmaf(qh[8],  k2.x, t0); t1 = fmaf(qh[9],  k2.y, t1);
      t0 = fmaf(qh[10], k2.z, t0); t1 = fmaf(qh[11], k2.w, t1);
      t0 = fmaf(qh[12], k3.x, t0); t1 = fmaf(qh[13], k3.y, t1);
      t0 = fmaf(qh[14], k3.z, t0); t1 = fmaf(qh[15], k3.w, t1);
      const float tv = t0 + t1;
      const float2 va = unpack2(pka[i]);
      const float2 vb = unpack2(pkb[i]);
      l0 = fmaf(tv, va.x, l0);
      l1 = fmaf(tv, va.y, l1);
      l2 = fmaf(tv, vb.x, l2);
      l3 = fmaf(tv, vb.y, l3);
    }
  }
  // ---- pass 2b: logits with Q[16..31] ----
  {
    float qh[16];
#pragma unroll
    for (int r = 0; r < 16; ++r)
      qh[r] = QsB[r * 32 + p] + QsB[512 + r * 32 + p];
#pragma unroll
    for (int i = 0; i < 16; ++i) {
      const float4 k0 = *(const float4*)(wkp + i * 32 + 16);
      const float4 k1 = *(const float4*)(wkp + i * 32 + 20);
      const float4 k2 = *(const float4*)(wkp + i * 32 + 24);
      const float4 k3 = *(const float4*)(wkp + i * 32 + 28);
      float t0 = 0.f, t1 = 0.f;
      t0 = fmaf(qh[0],  k0.x, t0); t1 = fmaf(qh[1],  k0.y, t1);
      t0 = fmaf(qh[2],  k0.z, t0); t1 = fmaf(qh[3],  k0.w, t1);
      t0 = fmaf(qh[4],  k1.x, t0); t1 = fmaf(qh[5],  k1.y, t1);
      t0 = fmaf(qh[6],  k1.z, t0); t1 = fmaf(qh[7],  k1.w, t1);
      t0 = fmaf(qh[8],  k2.x, t0); t1 = fmaf(qh[9],  k2.y, t1);
      t0 = fmaf(qh[10], k2.z, t0); t1 = fmaf(qh[11], k2.w, t1);
      t0 = fmaf(qh[12], k3.x, t0); t1 = fmaf(qh[13], k3.y, t1);
      t0 = fmaf(qh[14], k3.z, t0); t1 = fmaf(qh[15], k3.w, t1);
      const float tv = t0 + t1;
      const float2 va = unpack2(pka[i]);
      const float2 vb = unpack2(pkb[i]);
      l0 = fmaf(tv, va.x, l0);
      l1 = fmaf(tv, va.y, l1);
      l2 = fmaf(tv, vb.x, l2);
      l3 = fmaf(tv, vb.y, l3);
    }
  }
  __syncthreads();  // all QsA/QsB reads done -> safe to alias

  // ---- combine logits + softmax ----
  float* lbuf = QsA;  // [8 cq][32 p][4 s] = 4 KB
  *(float4*)(lbuf + (cq * 32 + p) * 4) = make_float4(l0, l1, l2, l3);
  __syncthreads();
  float* abuf = QsB;  // [32 p][4 s]
  if (tid < 32) {
    float L0 = 0.f, L1 = 0.f, L2 = 0.f, L3 = 0.f;
#pragma unroll
    for (int k = 0; k < 8; ++k) {
      const float4 s = *(const float4*)(lbuf + (k * 32 + tid) * 4);
      L0 += s.x; L1 += s.y; L2 += s.z; L3 += s.w;
    }
    const float mx = fmaxf(fmaxf(L0, L1), fmaxf(L2, L3));
    const float e0 = __expf(L0 - mx), e1 = __expf(L1 - mx);
    const float e2 = __expf(L2 - mx), e3 = __expf(L3 - mx);
    const float inv = 1.0f / ((e0 + e1) + (e2 + e3));
    *(float4*)(abuf + tid * 4) =
        make_float4(e0 * inv, e1 * inv, e2 * inv, e3 * inv);
  }
  __syncthreads();
  const float4 at = *(const float4*)(abuf + p * 4);

  // ---- pass 3: weighted window sum from stash -> out ----
  {
    float* op = out + ((size_t)(b * 128 + cb)) * 16384 + h * 128 + w0 + p;
#pragma unroll
    for (int i = 0; i < 16; ++i) {
      const float2 va = unpack2(pka[i]);
      const float2 vb = unpack2(pkb[i]);
      op[(size_t)i * 16384] =
          fmaf(at.x, va.x, fmaf(at.y, va.y, fmaf(at.z, vb.x, at.w * vb.y)));
    }
  }
}

extern "C" void kernel_launch(void* const* d_in, const int* in_sizes, int n_in,
                              void* d_out, int out_size, void* d_ws, size_t ws_size,
                              hipStream_t stream) {
  const float* fm = (const float*)d_in[0];
  const float* Wq = (const float*)d_in[1];
  const float* Wk = (const float*)d_in[2];
  float* outp = (float*)d_out;
  float* ws = (float*)d_ws;

  wt_kernel<<<16, 256, 0, stream>>>(Wq, Wk, ws);
  attn_main<<<4096, 256, 0, stream>>>(fm, ws, outp);
}

// Round 12
// 146.841 us; speedup vs baseline: 2.6676x; 2.6676x over previous
//
#include <hip/hip_runtime.h>
#include <hip/hip_bf16.h>
#include <math.h>

// AttentionDownSample: fm [8,128,256,256] f32, Wq/Wk [32,128] f32
// out [8,128,128,128] f32.
//
// r12: read-fm-once bf16 register stash, sized to the register allocator's
// LDS-driven occupancy heuristic (the r8/r9/r11 spill mechanism):
//   - 256-thr blocks (512-thr measured ~1 block/CU all session)
//   - 64 positions x 4 WAVE-UNIFORM channel groups (32 ch/thread) so weights
//     are SGPR s_load (lgkmcnt) and fm is vmcnt — separate counters (r7-proven)
//   - r-split: only 16 Q-accumulators/operands live at once (peak ~100 VGPR)
//   - dynamic LDS padded to 36 KB -> allocator targets 4 blocks/CU ->
//     128-VGPR budget -> NO spill (the only knob that reliably worked: r5/r10)
//   - 4 resident blocks at mixed phases: one block's load burst overlaps
//     other blocks' VALU phases (the overlap r10's 1-resident-block lacked)
//
// Per position: u[c]=v0+v1+v2+v3;  Q[r]=sum_c WqT'[c][r]u[c] (0.25/sqrt32
// folded);  t[c]=sum_r Q[r]WkT[c][r];  logit_s=sum_c t[c]v_s[c];
// out[c]=sum_s softmax(logit)_s v_s[c].  Logit is linear in the r-split.

typedef unsigned int uint32;

__device__ __forceinline__ uint32 pack2(float x, float y) {
  union { __hip_bfloat162 h; uint32 u; } cvt;
  cvt.h = __float22bfloat162_rn(make_float2(x, y));
  return cvt.u;
}
__device__ __forceinline__ float2 unpack2(uint32 u) {
  float2 r;
  r.x = __uint_as_float(u << 16);
  r.y = __uint_as_float(u & 0xffff0000u);
  return r;
}

__global__ __launch_bounds__(256) void wt_kernel(const float* __restrict__ Wq,
                                                 const float* __restrict__ Wk,
                                                 float* __restrict__ ws) {
  int t = blockIdx.x * 256 + threadIdx.x;  // 4096 threads, one (c,r) each
  if (t < 4096) {
    int c = t >> 5, r = t & 31;
    ws[c * 32 + r]        = Wq[r * 128 + c] * (0.25f / sqrtf(32.0f));
    ws[4096 + c * 32 + r] = Wk[r * 128 + c];
  }
}

__global__ __launch_bounds__(256)
void attn_main(const float* __restrict__ fm,
               const float* __restrict__ ws,
               float* __restrict__ out) {
  extern __shared__ float smem[];
  float* QA   = smem;          // [2][16][64] 8 KB (Q low half, tree)
  float* QB   = smem + 2048;   // [2][16][64] 8 KB (Q high half, tree)
  float* lbuf = smem + 4096;   // [4][64][4]  4 KB
  float* abuf = smem + 5120;   // [64][4]     1 KB  (rest of 36 KB = pad)

  const int tid = threadIdx.x;
  const int p   = tid & 63;                                  // position
  const int g   = __builtin_amdgcn_readfirstlane(tid >> 6);  // group 0..3

  const int blk = blockIdx.x;        // 2048 = 8 b * 128 h * 2 wt
  const int w0  = (blk & 1) * 64;
  const int h   = (blk >> 1) & 127;
  const int b   = blk >> 8;
  const int cb  = g * 32;

  const float* gbase = fm + ((size_t)(b * 128 + cb)) * 65536 +
                       (size_t)(2 * h) * 256 + 2 * (w0 + p);
  const float* wq = ws + cb * 32;          // WqT'[c][r] (wave-uniform addr)
  const float* wk = ws + 4096 + cb * 32;   // WkT[c][r]

  // ---- phase M: pure load+pack burst (max MLP), fm read EXACTLY once ----
  uint32 pka[32], pkb[32];
#pragma unroll
  for (int i = 0; i < 32; ++i) {
    const float2 va = *(const float2*)(gbase + (size_t)i * 65536);        // row0
    const float2 vb = *(const float2*)(gbase + (size_t)i * 65536 + 256);  // row1
    pka[i] = pack2(va.x, va.y);
    pkb[i] = pack2(vb.x, vb.y);
  }

  float qa[16];

  // ---- pass 1a: partial Q, r = 0..15 (weights via SGPR s_load) ----
#pragma unroll
  for (int r = 0; r < 16; ++r) qa[r] = 0.f;
#pragma unroll
  for (int i = 0; i < 32; ++i) {
    const float2 va = unpack2(pka[i]);
    const float2 vb = unpack2(pkb[i]);
    const float u = (va.x + va.y) + (vb.x + vb.y);
#pragma unroll
    for (int r = 0; r < 16; ++r)
      qa[r] = fmaf(wq[i * 32 + r], u, qa[r]);
  }
  if (g >= 2) {
#pragma unroll
    for (int r = 0; r < 16; ++r) QA[(g - 2) * 1024 + r * 64 + p] = qa[r];
  }
  __syncthreads();
  if (g < 2) {
#pragma unroll
    for (int r = 0; r < 16; ++r) QA[g * 1024 + r * 64 + p] += qa[r];
  }

  // ---- pass 1b: partial Q, r = 16..31 ----
#pragma unroll
  for (int r = 0; r < 16; ++r) qa[r] = 0.f;
#pragma unroll
  for (int i = 0; i < 32; ++i) {
    const float2 va = unpack2(pka[i]);
    const float2 vb = unpack2(pkb[i]);
    const float u = (va.x + va.y) + (vb.x + vb.y);
#pragma unroll
    for (int r = 0; r < 16; ++r)
      qa[r] = fmaf(wq[i * 32 + 16 + r], u, qa[r]);
  }
  __syncthreads();  // QA adds done; QB writes may start
  if (g >= 2) {
#pragma unroll
    for (int r = 0; r < 16; ++r) QB[(g - 2) * 1024 + r * 64 + p] = qa[r];
  }
  __syncthreads();
  if (g < 2) {
#pragma unroll
    for (int r = 0; r < 16; ++r) QB[g * 1024 + r * 64 + p] += qa[r];
  }
  __syncthreads();  // QA and QB final

  // ---- pass 2a: logits with Q[0..15] (qh from QA, halves summed) ----
  float l0 = 0.f, l1 = 0.f, l2 = 0.f, l3 = 0.f;
  {
    float qh[16];
#pragma unroll
    for (int r = 0; r < 16; ++r)
      qh[r] = QA[r * 64 + p] + QA[1024 + r * 64 + p];
#pragma unroll
    for (int i = 0; i < 32; ++i) {
      float t0 = 0.f, t1 = 0.f;
#pragma unroll
      for (int r = 0; r < 16; r += 2) {
        t0 = fmaf(qh[r + 0], wk[i * 32 + r + 0], t0);
        t1 = fmaf(qh[r + 1], wk[i * 32 + r + 1], t1);
      }
      const float tv = t0 + t1;
      const float2 va = unpack2(pka[i]);
      const float2 vb = unpack2(pkb[i]);
      l0 = fmaf(tv, va.x, l0);
      l1 = fmaf(tv, va.y, l1);
      l2 = fmaf(tv, vb.x, l2);
      l3 = fmaf(tv, vb.y, l3);
    }
  }
  // ---- pass 2b: logits with Q[16..31] (linear in r-split => exact) ----
  {
    float qh[16];
#pragma unroll
    for (int r = 0; r < 16; ++r)
      qh[r] = QB[r * 64 + p] + QB[1024 + r * 64 + p];
#pragma unroll
    for (int i = 0; i < 32; ++i) {
      float t0 = 0.f, t1 = 0.f;
#pragma unroll
      for (int r = 0; r < 16; r += 2) {
        t0 = fmaf(qh[r + 0], wk[i * 32 + 16 + r + 0], t0);
        t1 = fmaf(qh[r + 1], wk[i * 32 + 16 + r + 1], t1);
      }
      const float tv = t0 + t1;
      const float2 va = unpack2(pka[i]);
      const float2 vb = unpack2(pkb[i]);
      l0 = fmaf(tv, va.x, l0);
      l1 = fmaf(tv, va.y, l1);
      l2 = fmaf(tv, vb.x, l2);
      l3 = fmaf(tv, vb.y, l3);
    }
  }
  *(float4*)(lbuf + (g * 64 + p) * 4) = make_float4(l0, l1, l2, l3);
  __syncthreads();

  // ---- softmax (one wave combines the 4 groups, broadcasts via abuf) ----
  if (tid < 64) {
    const float4 s0 = *(const float4*)(lbuf + (0 * 64 + tid) * 4);
    const float4 s1 = *(const float4*)(lbuf + (1 * 64 + tid) * 4);
    const float4 s2 = *(const float4*)(lbuf + (2 * 64 + tid) * 4);
    const float4 s3 = *(const float4*)(lbuf + (3 * 64 + tid) * 4);
    const float L0 = (s0.x + s1.x) + (s2.x + s3.x);
    const float L1 = (s0.y + s1.y) + (s2.y + s3.y);
    const float L2 = (s0.z + s1.z) + (s2.z + s3.z);
    const float L3 = (s0.w + s1.w) + (s2.w + s3.w);
    const float mx = fmaxf(fmaxf(L0, L1), fmaxf(L2, L3));
    const float e0 = __expf(L0 - mx), e1 = __expf(L1 - mx);
    const float e2 = __expf(L2 - mx), e3 = __expf(L3 - mx);
    const float inv = 1.0f / ((e0 + e1) + (e2 + e3));
    *(float4*)(abuf + tid * 4) =
        make_float4(e0 * inv, e1 * inv, e2 * inv, e3 * inv);
  }
  __syncthreads();
  const float4 at = *(const float4*)(abuf + p * 4);

  // ---- pass 3: weighted window sum from stash -> out (coalesced) ----
  {
    float* op = out + ((size_t)(b * 128 + cb)) * 16384 + h * 128 + w0 + p;
#pragma unroll
    for (int i = 0; i < 32; ++i) {
      const float2 va = unpack2(pka[i]);
      const float2 vb = unpack2(pkb[i]);
      op[(size_t)i * 16384] =
          fmaf(at.x, va.x, fmaf(at.y, va.y, fmaf(at.z, vb.x, at.w * vb.y)));
    }
  }
}

extern "C" void kernel_launch(void* const* d_in, const int* in_sizes, int n_in,
                              void* d_out, int out_size, void* d_ws, size_t ws_size,
                              hipStream_t stream) {
  const float* fm = (const float*)d_in[0];
  const float* Wq = (const float*)d_in[1];
  const float* Wk = (const float*)d_in[2];
  float* outp = (float*)d_out;
  float* ws = (float*)d_ws;

  // 36 KB dynamic LDS: real use 21 KB, padded so the register allocator
  // targets 4 blocks/CU (128-VGPR budget) instead of 8 (64 -> spill).
  const int smem_bytes = 36864;
  wt_kernel<<<16, 256, 0, stream>>>(Wq, Wk, ws);
  attn_main<<<2048, 256, smem_bytes, stream>>>(fm, ws, outp);
}